// Round 17
// baseline (1448.253 us; speedup 1.0000x reference)
//
#include <hip/hip_runtime.h>
#include <hip/hip_bf16.h>
#include <math.h>

#define LN_EPS 1e-5f

typedef unsigned short u16;
typedef __attribute__((ext_vector_type(8))) _Float16 f16x8;
typedef __attribute__((ext_vector_type(4))) float f32x4;

__device__ __forceinline__ u16 f2h(float x) {
    _Float16 h = (_Float16)x;
    return __builtin_bit_cast(u16, h);
}
__device__ __forceinline__ void stv(float* p, float v) { *p = v; }
__device__ __forceinline__ void stv(u16* p, float v) { *p = f2h(v); }
__device__ __forceinline__ void stv4(float* p, float a, float b, float c, float d) {
    *(float4*)p = make_float4(a, b, c, d);
}
__device__ __forceinline__ void stv4(u16* p, float a, float b, float c, float d) {
    ushort4 o; o.x = f2h(a); o.y = f2h(b); o.z = f2h(c); o.w = f2h(d);
    *(ushort4*)p = o;
}

__device__ __forceinline__ float gelu_f(float x) {
    const float kA = 0.7978845608028654f;  // sqrt(2/pi)
    return 0.5f * x * (1.f + tanhf(kA * (x + 0.044715f * x * x * x)));
}

// async global->LDS, 16B per lane; LDS dest = wave-uniform base + lane*16
__device__ __forceinline__ void gl_lds16(const u16* g, u16* l) {
    __builtin_amdgcn_global_load_lds(
        (const __attribute__((address_space(1))) unsigned int*)g,
        (__attribute__((address_space(3))) unsigned int*)l, 16, 0, 0);
}
// counted vmem wait (T4)
template <int N> __device__ __forceinline__ void s_vmcnt() {
    asm volatile("s_waitcnt vmcnt(%0)" :: "n"(N) : "memory");
}
__device__ __forceinline__ void s_lgkm0() {
    asm volatile("s_waitcnt lgkmcnt(0)" ::: "memory");
    __builtin_amdgcn_sched_barrier(0);
}
__device__ __forceinline__ void bar() { __builtin_amdgcn_s_barrier(); }
__device__ __forceinline__ void sfence() { __builtin_amdgcn_sched_barrier(0); }

// ------- one 64x64 transpose-convert tile: fp32 W[K][N] -> fp16 Wt[N][K] ----------
__device__ __forceinline__ void cvt_tile(int t, const float* __restrict__ Wqkv,
                                         const float* __restrict__ Wo,
                                         const float* __restrict__ Wfc,
                                         const float* __restrict__ Wmp,
                                         u16* __restrict__ dst, float (*tile)[65]) {
    const float* W; u16* Wt; int K, N, idx;
    if (t < 768)       { W = Wqkv; Wt = dst;           K = 1024; N = 3072; idx = t; }
    else if (t < 1024) { W = Wo;   Wt = dst + 3145728; K = 1024; N = 1024; idx = t - 768; }
    else if (t < 2048) { W = Wfc;  Wt = dst + 4194304; K = 1024; N = 4096; idx = t - 1024; }
    else               { W = Wmp;  Wt = dst + 8388608; K = 4096; N = 1024; idx = t - 2048; }
    int ntn = N >> 6;
    int n0 = (idx % ntn) * 64, k0 = (idx / ntn) * 64;
    int th = threadIdx.x;
    int r = th >> 4, c4 = (th & 15) * 4;
#pragma unroll
    for (int p = 0; p < 4; p++) {
        float4 v = *(const float4*)(W + (size_t)(k0 + p * 16 + r) * N + n0 + c4);
        tile[p * 16 + r][c4 + 0] = v.x;
        tile[p * 16 + r][c4 + 1] = v.y;
        tile[p * 16 + r][c4 + 2] = v.z;
        tile[p * 16 + r][c4 + 3] = v.w;
    }
    __syncthreads();
#pragma unroll
    for (int p = 0; p < 4; p++) {
        int n = p * 16 + r;
        ushort4 o;
        o.x = f2h(tile[c4 + 0][n]);
        o.y = f2h(tile[c4 + 1][n]);
        o.z = f2h(tile[c4 + 2][n]);
        o.w = f2h(tile[c4 + 3][n]);
        *(ushort4*)(Wt + (size_t)(n0 + n) * K + k0 + c4) = o;
    }
}

// ------- standalone weight convert (prologue, layer 0): 3072 tiles ----------
__global__ __launch_bounds__(256) void tr_cvt_all(
    const float* __restrict__ Wqkv, const float* __restrict__ Wo,
    const float* __restrict__ Wfc, const float* __restrict__ Wmp,
    u16* __restrict__ dst) {
    __shared__ float tile[64][65];
    cvt_tile(blockIdx.x, Wqkv, Wo, Wfc, Wmp, dst, tile);
}

// ---------------- LayerNorm (wave-per-row) + fused next-layer weight convert ----------
// Blocks [0,256): LN rows. Blocks [256, ...): convert tile (id-256+cbase) into cdst.
// PARTS: number of split-K partial buffers to reduce (0, 2, or 4); partial i at
// p + i*(1<<20). xnew = x + sum(partials), x updated in place.
template <int PARTS, typename OT>
__global__ __launch_bounds__(256) void ln_cvt(float* __restrict__ x,
                                              const float* __restrict__ p,
                                              const float* __restrict__ gam,
                                              const float* __restrict__ bet,
                                              OT* __restrict__ out,
                                              const float* __restrict__ cWq,
                                              const float* __restrict__ cWo,
                                              const float* __restrict__ cWf,
                                              const float* __restrict__ cWm,
                                              u16* __restrict__ cdst, int cbase) {
    __shared__ float tile[64][65];
    if (blockIdx.x >= 256) {
        cvt_tile(blockIdx.x - 256 + cbase, cWq, cWo, cWf, cWm, cdst, tile);
        return;
    }
    int w = threadIdx.x >> 6, lane = threadIdx.x & 63;
    int row = blockIdx.x * 4 + w;
    size_t base = (size_t)row * 1024;
    float4 v[4];
    float s = 0.f, ss = 0.f;
#pragma unroll
    for (int j = 0; j < 4; j++) {
        int c = lane * 4 + j * 256;
        float4 xv = *(const float4*)(x + base + c);
        if (PARTS) {
#pragma unroll
            for (int i = 0; i < PARTS; i++) {
                float4 a = *(const float4*)(p + (size_t)i * (1u << 20) + base + c);
                xv.x += a.x; xv.y += a.y; xv.z += a.z; xv.w += a.w;
            }
            *(float4*)(x + base + c) = xv;   // materialize residual stream
        }
        v[j] = xv;
        s += xv.x + xv.y + xv.z + xv.w;
        ss += xv.x * xv.x + xv.y * xv.y + xv.z * xv.z + xv.w * xv.w;
    }
#pragma unroll
    for (int off = 32; off > 0; off >>= 1) {
        s += __shfl_xor(s, off);
        ss += __shfl_xor(ss, off);
    }
    float mu = s * (1.f / 1024.f);
    float var = ss * (1.f / 1024.f) - mu * mu;
    float rstd = rsqrtf(var + LN_EPS);
#pragma unroll
    for (int j = 0; j < 4; j++) {
        int c = lane * 4 + j * 256;
        float4 gv = *(const float4*)(gam + c);
        float4 bv = *(const float4*)(bet + c);
        stv4(&out[base + c],
             (v[j].x - mu) * rstd * gv.x + bv.x,
             (v[j].y - mu) * rstd * gv.y + bv.y,
             (v[j].z - mu) * rstd * gv.z + bv.z,
             (v[j].w - mu) * rstd * gv.w + bv.w);
    }
}

// ---------------- fp16 MFMA GEMM, 2-phase pipelined, WROWxWCOL wave grid ----------------
template <int BM, int BN, int BK, int WROW, int WCOL, int ACT, int WVT, int SPLITK,
          typename OT>
__global__ __launch_bounds__(WROW * WCOL * 64) void gemm_f16(
    const u16* __restrict__ A, const u16* __restrict__ Bt,
    const float* __restrict__ bias, OT* __restrict__ out,
    u16* __restrict__ vTout, int M, int N, int K) {
    __shared__ u16 As[2][BM * BK];
    __shared__ u16 Bs[2][BN * BK];
    constexpr int THREADS = WROW * WCOL * 64;
    constexpr int WM = BM / WROW, WN = BN / WCOL;
    constexpr int FM = WM / 16, FN = WN / 16;
    constexpr int NKF = BK / 32;
    constexpr int SLOTS = BK / 8;
    constexpr int ACH = BM * BK / 8 / THREADS;
    constexpr int BCH = BN * BK / 8 / THREADS;
    constexpr int LPS = ACH + BCH;
    int tid = threadIdx.x;
    int w = tid >> 6, l = tid & 63;
    int wm = w / WCOL, wn = w % WCOL;
    int lr = l & 15, g = l >> 4;
    int m0 = blockIdx.y * BM, n0 = blockIdx.x * BN;
    int kbase = (SPLITK > 1) ? blockIdx.z * (K / SPLITK) : 0;
    int Kc = (SPLITK > 1) ? (K / SPLITK) : K;
    OT* outz = (SPLITK > 1) ? out + (size_t)blockIdx.z * M * N : out;

    f32x4 acc[FM][FN] = {};

    auto stage = [&](int buf, int k0) {
#pragma unroll
        for (int i = 0; i < ACH; i++) {
            int chunk = i * THREADS + tid;
            int row = chunk / SLOTS, s = chunk % SLOTS, sg = s ^ (row & 7);
            gl_lds16(A + (size_t)(m0 + row) * K + kbase + k0 + sg * 8, &As[buf][chunk * 8]);
        }
#pragma unroll
        for (int i = 0; i < BCH; i++) {
            int chunk = i * THREADS + tid;
            int row = chunk / SLOTS, s = chunk % SLOTS, sg = s ^ (row & 7);
            gl_lds16(Bt + (size_t)(n0 + row) * K + kbase + k0 + sg * 8, &Bs[buf][chunk * 8]);
        }
    };

    int NT = Kc / BK;
    stage(0, 0);
    int cur = 0;
    for (int t = 0; t < NT; t++) {
        if (t + 1 < NT) { stage(cur ^ 1, (t + 1) * BK); s_vmcnt<LPS>(); }
        else            { s_vmcnt<0>(); }
        bar();      // tile t staged by all waves
        sfence();

        const u16* Ab = &As[cur][0];
        const u16* Bb = &Bs[cur][0];
        f16x8 af[FM][NKF], bfrag[FN][NKF];
#pragma unroll
        for (int m = 0; m < FM; m++)
#pragma unroll
            for (int kf = 0; kf < NKF; kf++) {
                int row = wm * WM + m * 16 + lr;
                af[m][kf] = *(const f16x8*)(Ab + row * BK + (((kf * 4 + g) ^ (row & 7)) * 8));
            }
#pragma unroll
        for (int n = 0; n < FN; n++)
#pragma unroll
            for (int kf = 0; kf < NKF; kf++) {
                int row = wn * WN + n * 16 + lr;
                bfrag[n][kf] = *(const f16x8*)(Bb + row * BK + (((kf * 4 + g) ^ (row & 7)) * 8));
            }
#pragma unroll
        for (int kf = 0; kf < NKF; kf++)
#pragma unroll
            for (int m = 0; m < FM; m++)
#pragma unroll
                for (int n = 0; n < FN; n++)
                    acc[m][n] = __builtin_amdgcn_mfma_f32_16x16x32_f16(
                        af[m][kf], bfrag[n][kf], acc[m][n], 0, 0, 0);

        sfence();
        bar();      // all waves done reading buf[cur] before re-stage
        cur ^= 1;
    }

#pragma unroll
    for (int m = 0; m < FM; m++) {
#pragma unroll
        for (int n = 0; n < FN; n++) {
            int col = n0 + wn * WN + n * 16 + lr;
            int row0 = m0 + wm * WM + m * 16 + 4 * g;
            float bv = (SPLITK > 1 && blockIdx.z != 0) ? 0.f : bias[col];
            u16 hv[4];
#pragma unroll
            for (int r = 0; r < 4; r++) {
                float v = acc[m][n][r] + bv;
                if (ACT) v = gelu_f(v);
                stv(&outz[(size_t)(row0 + r) * N + col], v);
                if (WVT) hv[r] = f2h(v);
            }
            if (WVT && col >= 2048) {
                ushort4 pv; pv.x = hv[0]; pv.y = hv[1]; pv.z = hv[2]; pv.w = hv[3];
                *(ushort4*)(vTout + (size_t)(col - 2048) * 1024 + row0) = pv;
            }
        }
    }
}

// ---------------- flash MFMA attention, KV-split over blockIdx.z ----------------
// z in {0,1}: keys [z*512, z*512+512) as 4 chunks of 128. Writes unnormalized fp32
// O to po + z*1M and per-row (m,l) to mlb[z*16384 + row*16 + h].
__global__ __launch_bounds__(256) void attn_mfma(
    const u16* __restrict__ qkv, const u16* __restrict__ vT,
    const float* __restrict__ mask, float* __restrict__ po,
    float2* __restrict__ mlb) {
    int h = blockIdx.y;
    int q0 = blockIdx.x * 64;
    int bz = blockIdx.z;
    int tid = threadIdx.x;
    int w = tid >> 6, l = tid & 63;
    int lr = l & 15, g = l >> 4;

    __shared__ u16 Ks[2][128 * 64];   // [key][d], 8 slots/row
    __shared__ u16 Vs[2][64 * 128];   // [d][key], 16 slots/row
    __shared__ u16 Ps[4 * 16 * 128];  // per-wave P: [q][key], 16 slots/row
    __shared__ float maskb[1024];

    for (int i = tid; i < 1024; i += 256) maskb[i] = -1e9f * (1.f - mask[i]);
    s_lgkm0();

    f16x8 qf[2];
#pragma unroll
    for (int kf = 0; kf < 2; kf++)
        qf[kf] = *(const f16x8*)(qkv + (size_t)(q0 + w * 16 + lr) * 3072 + h * 64 + kf * 32 + g * 8);

    f32x4 o[4] = {};
    float mrow[4], lrow[4];
#pragma unroll
    for (int r = 0; r < 4; r++) { mrow[r] = -1e30f; lrow[r] = 0.f; }

    u16* Psw = Ps + w * 2048;

    auto stage = [&](int buf, int kc) {
#pragma unroll
        for (int i = 0; i < 4; i++) {
            int chunk = i * 256 + tid;
            int krow = chunk >> 3, ks = chunk & 7, ksg = ks ^ (krow & 7);
            gl_lds16(qkv + (size_t)(kc * 128 + krow) * 3072 + 1024 + h * 64 + ksg * 8,
                     &Ks[buf][chunk * 8]);
            int vrow = chunk >> 4, vs = chunk & 15, vsg = vs ^ (vrow & 7);
            gl_lds16(vT + (size_t)(h * 64 + vrow) * 1024 + kc * 128 + vsg * 8,
                     &Vs[buf][chunk * 8]);
        }
    };

    stage(0, bz * 4);
    int cur = 0;
    for (int kcl = 0; kcl < 4; kcl++) {
        int kc = bz * 4 + kcl;
        if (kcl + 1 < 4) { stage(cur ^ 1, kc + 1); s_vmcnt<8>(); }
        else             { s_vmcnt<0>(); }
        bar();
        sfence();
        const u16* Kb = &Ks[cur][0];
        const u16* Vb = &Vs[cur][0];

        f32x4 s[8] = {};
        __builtin_amdgcn_s_setprio(1);
#pragma unroll
        for (int n = 0; n < 8; n++)
#pragma unroll
            for (int kf = 0; kf < 2; kf++) {
                int row = n * 16 + lr;
                f16x8 kfrag = *(const f16x8*)(Kb + row * 64 + (((kf * 4 + g) ^ (row & 7)) * 8));
                s[n] = __builtin_amdgcn_mfma_f32_16x16x32_f16(qf[kf], kfrag, s[n], 0, 0, 0);
            }
        __builtin_amdgcn_s_setprio(0);

        float mcol[8];
#pragma unroll
        for (int n = 0; n < 8; n++) mcol[n] = maskb[kc * 128 + n * 16 + lr];

        float scl[4], mnew[4], psum[4];
#pragma unroll
        for (int r = 0; r < 4; r++) {
            float mx = -1e30f;
#pragma unroll
            for (int n = 0; n < 8; n++) {
                float sv = s[n][r] * 0.125f + mcol[n];
                s[n][r] = sv;
                mx = fmaxf(mx, sv);
            }
            mx = fmaxf(mx, __shfl_xor(mx, 1));
            mx = fmaxf(mx, __shfl_xor(mx, 2));
            mx = fmaxf(mx, __shfl_xor(mx, 4));
            mx = fmaxf(mx, __shfl_xor(mx, 8));
            mnew[r] = fmaxf(mrow[r], mx);
            scl[r] = __expf(mrow[r] - mnew[r]);
            mrow[r] = mnew[r];
            psum[r] = 0.f;
        }
#pragma unroll
        for (int n = 0; n < 8; n++) {
            float p0 = __expf(s[n][0] - mnew[0]);
            float p1 = __expf(s[n][1] - mnew[1]);
            float p2 = __expf(s[n][2] - mnew[2]);
            float p3 = __expf(s[n][3] - mnew[3]);
            psum[0] += p0; psum[1] += p1; psum[2] += p2; psum[3] += p3;
            int col = n * 16 + lr, cs = col >> 3, cl = col & 7;
            int r0 = 4 * g;
            Psw[(r0 + 0) * 128 + ((cs ^ ((r0 + 0) & 7)) * 8) + cl] = f2h(p0);
            Psw[(r0 + 1) * 128 + ((cs ^ ((r0 + 1) & 7)) * 8) + cl] = f2h(p1);
            Psw[(r0 + 2) * 128 + ((cs ^ ((r0 + 2) & 7)) * 8) + cl] = f2h(p2);
            Psw[(r0 + 3) * 128 + ((cs ^ ((r0 + 3) & 7)) * 8) + cl] = f2h(p3);
        }
#pragma unroll
        for (int r = 0; r < 4; r++) {
            float ps_ = psum[r];
            ps_ += __shfl_xor(ps_, 1);
            ps_ += __shfl_xor(ps_, 2);
            ps_ += __shfl_xor(ps_, 4);
            ps_ += __shfl_xor(ps_, 8);
            lrow[r] = lrow[r] * scl[r] + ps_;
#pragma unroll
            for (int dn = 0; dn < 4; dn++) o[dn][r] *= scl[r];
        }

        f16x8 pa[4];
#pragma unroll
        for (int kf = 0; kf < 4; kf++)
            pa[kf] = *(const f16x8*)(Psw + lr * 128 + (((kf * 4 + g) ^ (lr & 7)) * 8));
        __builtin_amdgcn_s_setprio(1);
#pragma unroll
        for (int dn = 0; dn < 4; dn++) {
#pragma unroll
            for (int kf = 0; kf < 4; kf++) {
                int row = dn * 16 + lr;
                f16x8 vb = *(const f16x8*)(Vb + row * 128 + (((kf * 4 + g) ^ (row & 7)) * 8));
                o[dn] = __builtin_amdgcn_mfma_f32_16x16x32_f16(pa[kf], vb, o[dn], 0, 0, 0);
            }
        }
        __builtin_amdgcn_s_setprio(0);

        sfence();
        bar();
        cur ^= 1;
    }

    float* poz = po + (size_t)bz * (1u << 20);
#pragma unroll
    for (int dn = 0; dn < 4; dn++)
#pragma unroll
        for (int r = 0; r < 4; r++) {
            int row = q0 + w * 16 + 4 * g + r;
            int col = h * 64 + dn * 16 + lr;
            poz[(size_t)row * 1024 + col] = o[dn][r];
        }
    if (lr == 0) {
#pragma unroll
        for (int r = 0; r < 4; r++) {
            int row = q0 + w * 16 + 4 * g + r;
            mlb[bz * 16384 + row * 16 + h] = make_float2(mrow[r], lrow[r]);
        }
    }
}

// ---------------- merge of the two KV-split halves -> fp16 y ----------------
__global__ __launch_bounds__(256) void attn_merge(const float* __restrict__ po,
                                                  const float2* __restrict__ mlb,
                                                  u16* __restrict__ y) {
    int w = threadIdx.x >> 6, lane = threadIdx.x & 63;
    int row = blockIdx.x * 4 + w;
    size_t base = (size_t)row * 1024;
#pragma unroll
    for (int j = 0; j < 4; j++) {
        int c = lane * 4 + j * 256;
        int h = c >> 6;
        float2 a = mlb[row * 16 + h];
        float2 b = mlb[16384 + row * 16 + h];
        float m = fmaxf(a.x, b.x);
        float w0 = __expf(a.x - m), w1 = __expf(b.x - m);
        float inv = 1.f / (w0 * a.y + w1 * b.y);
        float4 o0 = *(const float4*)(po + base + c);
        float4 o1 = *(const float4*)(po + (1u << 20) + base + c);
        stv4(&y[base + c],
             (w0 * o0.x + w1 * o1.x) * inv,
             (w0 * o0.y + w1 * o1.y) * inv,
             (w0 * o0.z + w1 * o1.z) * inv,
             (w0 * o0.w + w1 * o1.w) * inv);
    }
}

// ---------------- launch ----------------
extern "C" void kernel_launch(void* const* d_in, const int* in_sizes, int n_in,
                              void* d_out, int out_size, void* d_ws, size_t ws_size,
                              hipStream_t stream) {
    const float* inputs_embeds = (const float*)d_in[0];
    const float* attn_mask     = (const float*)d_in[1];
    const float* ln1_g = (const float*)d_in[2];
    const float* ln1_b = (const float*)d_in[3];
    const float* Wqkv  = (const float*)d_in[4];
    const float* bqkv  = (const float*)d_in[5];
    const float* Wo    = (const float*)d_in[6];
    const float* bo    = (const float*)d_in[7];
    const float* ln2_g = (const float*)d_in[8];
    const float* ln2_b = (const float*)d_in[9];
    const float* Wfc   = (const float*)d_in[10];
    const float* bfc   = (const float*)d_in[11];
    const float* Wmp   = (const float*)d_in[12];
    const float* bmp   = (const float*)d_in[13];
    const float* lnf_g = (const float*)d_in[14];
    const float* lnf_b = (const float*)d_in[15];
    float* out = (float*)d_out;

    char* ws = (char*)d_ws;
    float* x   = (float*)ws;                              // 4 MB fp32 residual
    u16* hbuf  = (u16*)(ws + (4u << 20));                 // 2 MB fp16 (ln out / attn y)
    u16* qkvb  = (u16*)(ws + (6u << 20));                 // 8 MB (qkv 6MB | fc 8MB)
    u16* fcb   = qkvb;
    u16* ybuf  = hbuf;
    u16* vTb   = (u16*)(ws + (14u << 20));                // 2 MB [1024 d][1024 key]
    u16* wbuf0 = (u16*)(ws + (16u << 20));                // 24 MB weights (even layers)
    u16* wbuf1 = (u16*)(ws + (40u << 20));                // 24 MB weights (odd layers)
    float* pP  = (float*)(ws + (64u << 20));              // 8 MB proj partials (2x 4MB)
    float* pM  = (float*)(ws + (72u << 20));              // 16 MB MP partials (4x 4MB)
    float* po  = (float*)(ws + (88u << 20));              // 8 MB attn O partials (2x 4MB)
    float2* ml = (float2*)(ws + (96u << 20));             // 256 KB attn (m,l)

    hipMemcpyAsync(x, inputs_embeds, (size_t)(1 << 20) * sizeof(float),
                   hipMemcpyDeviceToDevice, stream);

    // prologue: layer 0 weights -> wbuf0
    tr_cvt_all<<<3072, 256, 0, stream>>>(Wqkv, Wo, Wfc, Wmp, wbuf0);

    for (int l = 0; l < 12; l++) {
        u16* wb = (l & 1) ? wbuf1 : wbuf0;
        u16* wq = wb, *wo_ = wb + 3145728, *wf = wb + 4194304, *wm = wb + 8388608;

        bool cv = (l + 1 < 12);
        u16* nb = ((l + 1) & 1) ? wbuf1 : wbuf0;
        const float* nWq = cv ? Wqkv + (size_t)(l + 1) * 3145728 : nullptr;
        const float* nWo = cv ? Wo   + (size_t)(l + 1) * 1048576 : nullptr;
        const float* nWf = cv ? Wfc  + (size_t)(l + 1) * 4194304 : nullptr;
        const float* nWm = cv ? Wmp  + (size_t)(l + 1) * 4194304 : nullptr;
        int grid_ln = cv ? 256 + 1536 : 256;

        // ln1 (+ convert tiles 0..1535 of layer l+1); l>0 reduces 4 MP partials
        if (l == 0)
            ln_cvt<0, u16><<<grid_ln, 256, 0, stream>>>(
                x, nullptr, ln1_g + l * 1024, ln1_b + l * 1024, hbuf,
                nWq, nWo, nWf, nWm, nb, 0);
        else
            ln_cvt<4, u16><<<grid_ln, 256, 0, stream>>>(
                x, pM, ln1_g + l * 1024, ln1_b + l * 1024, hbuf,
                nWq, nWo, nWf, nWm, nb, 0);

        // QKV: 1024x3072, 64x128 tiles, 8 waves (2x4) -> 384 blocks x 512 thr; fused vT
        gemm_f16<64, 128, 64, 2, 4, 0, 1, 1, u16><<<dim3(24, 16), 512, 0, stream>>>(
            hbuf, wq, bqkv + (size_t)l * 3072, qkvb, vTb, 1024, 3072, 1024);
        // attn: KV-split x2 -> 512 blocks; merge -> ybuf
        attn_mfma<<<dim3(16, 16, 2), 256, 0, stream>>>(qkvb, vTb, attn_mask, po, ml);
        attn_merge<<<256, 256, 0, stream>>>(po, ml, ybuf);
        // proj: 1024x1024, 64x64 tiles, BK=128, splitK=2 -> 512 blocks, fp32 partials
        gemm_f16<64, 64, 128, 2, 2, 0, 0, 2, float><<<dim3(16, 16, 2), 256, 0, stream>>>(
            ybuf, wo_, bo + (size_t)l * 1024, pP, nullptr, 1024, 1024, 1024);
        // ln2 (+ convert tiles 1536..3071 of layer l+1); reduces 2 proj partials
        ln_cvt<2, u16><<<grid_ln, 256, 0, stream>>>(
            x, pP, ln2_g + l * 1024, ln2_b + l * 1024, hbuf,
            nWq, nWo, nWf, nWm, nb, 1536);
        // FC: 1024x4096, 128x128 tiles, 8 waves (2x4) -> 256 blocks x 512 thr
        gemm_f16<128, 128, 64, 2, 4, 1, 0, 1, u16><<<dim3(32, 8), 512, 0, stream>>>(
            hbuf, wf, bfc + (size_t)l * 4096, fcb, nullptr, 1024, 4096, 1024);
        // MP: 1024x1024 (K=4096), 64x64 tiles, BK=128, splitK=4 -> 1024 blocks
        gemm_f16<64, 64, 128, 2, 2, 0, 0, 4, float><<<dim3(16, 16, 4), 256, 0, stream>>>(
            fcb, wm, bmp + (size_t)l * 1024, pM, nullptr, 1024, 1024, 4096);
    }
    // final LN reduces layer-11's 4 MP partials (no convert blocks)
    ln_cvt<4, float><<<256, 256, 0, stream>>>(
        x, pM, lnf_g, lnf_b, out,
        nullptr, nullptr, nullptr, nullptr, nullptr, 0);
}

// Round 18
// 1332.078 us; speedup vs baseline: 1.0872x; 1.0872x over previous
//
#include <hip/hip_runtime.h>
#include <hip/hip_bf16.h>
#include <math.h>

#define LN_EPS 1e-5f

typedef unsigned short u16;
typedef __attribute__((ext_vector_type(8))) _Float16 f16x8;
typedef __attribute__((ext_vector_type(4))) float f32x4;

__device__ __forceinline__ u16 f2h(float x) {
    _Float16 h = (_Float16)x;
    return __builtin_bit_cast(u16, h);
}
__device__ __forceinline__ void stv(float* p, float v) { *p = v; }
__device__ __forceinline__ void stv(u16* p, float v) { *p = f2h(v); }
__device__ __forceinline__ void stv4(float* p, float a, float b, float c, float d) {
    *(float4*)p = make_float4(a, b, c, d);
}
__device__ __forceinline__ void stv4(u16* p, float a, float b, float c, float d) {
    ushort4 o; o.x = f2h(a); o.y = f2h(b); o.z = f2h(c); o.w = f2h(d);
    *(ushort4*)p = o;
}

__device__ __forceinline__ float gelu_f(float x) {
    const float kA = 0.7978845608028654f;  // sqrt(2/pi)
    return 0.5f * x * (1.f + tanhf(kA * (x + 0.044715f * x * x * x)));
}

// async global->LDS, 16B per lane; LDS dest = wave-uniform base + lane*16
__device__ __forceinline__ void gl_lds16(const u16* g, u16* l) {
    __builtin_amdgcn_global_load_lds(
        (const __attribute__((address_space(1))) unsigned int*)g,
        (__attribute__((address_space(3))) unsigned int*)l, 16, 0, 0);
}
// counted vmem wait (T4)
template <int N> __device__ __forceinline__ void s_vmcnt() {
    asm volatile("s_waitcnt vmcnt(%0)" :: "n"(N) : "memory");
}
__device__ __forceinline__ void s_lgkm0() {
    asm volatile("s_waitcnt lgkmcnt(0)" ::: "memory");
    __builtin_amdgcn_sched_barrier(0);
}
__device__ __forceinline__ void bar() { __builtin_amdgcn_s_barrier(); }
__device__ __forceinline__ void sfence() { __builtin_amdgcn_sched_barrier(0); }

// ------- one 64x64 transpose-convert tile: fp32 W[K][N] -> fp16 Wt[N][K] ----------
// Tile id t in [0,3072): 0-767 qkv | 768-1023 wo | 1024-2047 wfc | 2048-3071 wmp.
// dst is the 24MB weight-buffer base (u16): wq +0, wo +3145728, wf +4194304, wm +8388608.
__device__ __forceinline__ void cvt_tile(int t, const float* __restrict__ Wqkv,
                                         const float* __restrict__ Wo,
                                         const float* __restrict__ Wfc,
                                         const float* __restrict__ Wmp,
                                         u16* __restrict__ dst, float (*tile)[65]) {
    const float* W; u16* Wt; int K, N, idx;
    if (t < 768)       { W = Wqkv; Wt = dst;           K = 1024; N = 3072; idx = t; }
    else if (t < 1024) { W = Wo;   Wt = dst + 3145728; K = 1024; N = 1024; idx = t - 768; }
    else if (t < 2048) { W = Wfc;  Wt = dst + 4194304; K = 1024; N = 4096; idx = t - 1024; }
    else               { W = Wmp;  Wt = dst + 8388608; K = 4096; N = 1024; idx = t - 2048; }
    int ntn = N >> 6;
    int n0 = (idx % ntn) * 64, k0 = (idx / ntn) * 64;
    int th = threadIdx.x;
    int r = th >> 4, c4 = (th & 15) * 4;
#pragma unroll
    for (int p = 0; p < 4; p++) {
        float4 v = *(const float4*)(W + (size_t)(k0 + p * 16 + r) * N + n0 + c4);
        tile[p * 16 + r][c4 + 0] = v.x;
        tile[p * 16 + r][c4 + 1] = v.y;
        tile[p * 16 + r][c4 + 2] = v.z;
        tile[p * 16 + r][c4 + 3] = v.w;
    }
    __syncthreads();
#pragma unroll
    for (int p = 0; p < 4; p++) {
        int n = p * 16 + r;
        ushort4 o;
        o.x = f2h(tile[c4 + 0][n]);
        o.y = f2h(tile[c4 + 1][n]);
        o.z = f2h(tile[c4 + 2][n]);
        o.w = f2h(tile[c4 + 3][n]);
        *(ushort4*)(Wt + (size_t)(n0 + n) * K + k0 + c4) = o;
    }
}

// ------- standalone weight convert (prologue, layer 0): 3072 tiles ----------
__global__ __launch_bounds__(256) void tr_cvt_all(
    const float* __restrict__ Wqkv, const float* __restrict__ Wo,
    const float* __restrict__ Wfc, const float* __restrict__ Wmp,
    u16* __restrict__ dst) {
    __shared__ float tile[64][65];
    cvt_tile(blockIdx.x, Wqkv, Wo, Wfc, Wmp, dst, tile);
}

// ---------------- LayerNorm (wave-per-row) + fused next-layer weight convert ----------
// Blocks [0,256): LN rows. Blocks [256, 256+ncvt): convert tile (id-256+cbase) of the
// NEXT layer's weights into cdst. PART=1: xnew = x + p0 + p1, x updated in place.
template <int PART, typename OT>
__global__ __launch_bounds__(256) void ln_cvt(float* __restrict__ x,
                                              const float* __restrict__ p0,
                                              const float* __restrict__ p1,
                                              const float* __restrict__ gam,
                                              const float* __restrict__ bet,
                                              OT* __restrict__ out,
                                              const float* __restrict__ cWq,
                                              const float* __restrict__ cWo,
                                              const float* __restrict__ cWf,
                                              const float* __restrict__ cWm,
                                              u16* __restrict__ cdst, int cbase) {
    __shared__ float tile[64][65];
    if (blockIdx.x >= 256) {
        cvt_tile(blockIdx.x - 256 + cbase, cWq, cWo, cWf, cWm, cdst, tile);
        return;
    }
    int w = threadIdx.x >> 6, lane = threadIdx.x & 63;
    int row = blockIdx.x * 4 + w;
    size_t base = (size_t)row * 1024;
    float4 v[4];
    float s = 0.f, ss = 0.f;
#pragma unroll
    for (int j = 0; j < 4; j++) {
        int c = lane * 4 + j * 256;
        float4 xv = *(const float4*)(x + base + c);
        if (PART) {
            float4 a = *(const float4*)(p0 + base + c);
            float4 b = *(const float4*)(p1 + base + c);
            xv.x += a.x + b.x; xv.y += a.y + b.y;
            xv.z += a.z + b.z; xv.w += a.w + b.w;
            *(float4*)(x + base + c) = xv;   // materialize residual stream
        }
        v[j] = xv;
        s += xv.x + xv.y + xv.z + xv.w;
        ss += xv.x * xv.x + xv.y * xv.y + xv.z * xv.z + xv.w * xv.w;
    }
#pragma unroll
    for (int off = 32; off > 0; off >>= 1) {
        s += __shfl_xor(s, off);
        ss += __shfl_xor(ss, off);
    }
    float mu = s * (1.f / 1024.f);
    float var = ss * (1.f / 1024.f) - mu * mu;
    float rstd = rsqrtf(var + LN_EPS);
#pragma unroll
    for (int j = 0; j < 4; j++) {
        int c = lane * 4 + j * 256;
        float4 gv = *(const float4*)(gam + c);
        float4 bv = *(const float4*)(bet + c);
        stv4(&out[base + c],
             (v[j].x - mu) * rstd * gv.x + bv.x,
             (v[j].y - mu) * rstd * gv.y + bv.y,
             (v[j].z - mu) * rstd * gv.z + bv.z,
             (v[j].w - mu) * rstd * gv.w + bv.w);
    }
}

// ---------------- fp16 MFMA GEMM, 2-phase pipelined, WROWxWCOL wave grid ----------------
// out[M,N] = A[M,K] @ Bt[N,K]^T + bias. THREADS = WROW*WCOL*64.
// SPLITK>1: blockIdx.z picks K-chunk; output -> out + z*M*N (fp32 partials, bias on z==0).
// k-slot swizzle (slot ^ (row&7)) applied on the GLOBAL source address.
template <int BM, int BN, int BK, int WROW, int WCOL, int ACT, int WVT, int SPLITK,
          typename OT>
__global__ __launch_bounds__(WROW * WCOL * 64) void gemm_f16(
    const u16* __restrict__ A, const u16* __restrict__ Bt,
    const float* __restrict__ bias, OT* __restrict__ out,
    u16* __restrict__ vTout, int M, int N, int K) {
    __shared__ u16 As[2][BM * BK];
    __shared__ u16 Bs[2][BN * BK];
    constexpr int THREADS = WROW * WCOL * 64;
    constexpr int WM = BM / WROW, WN = BN / WCOL;
    constexpr int FM = WM / 16, FN = WN / 16;
    constexpr int NKF = BK / 32;
    constexpr int SLOTS = BK / 8;
    constexpr int ACH = BM * BK / 8 / THREADS;
    constexpr int BCH = BN * BK / 8 / THREADS;
    constexpr int LPS = ACH + BCH;
    int tid = threadIdx.x;
    int w = tid >> 6, l = tid & 63;
    int wm = w / WCOL, wn = w % WCOL;
    int lr = l & 15, g = l >> 4;
    int m0 = blockIdx.y * BM, n0 = blockIdx.x * BN;
    int kbase = (SPLITK > 1) ? blockIdx.z * (K / SPLITK) : 0;
    int Kc = (SPLITK > 1) ? (K / SPLITK) : K;
    OT* outz = (SPLITK > 1) ? out + (size_t)blockIdx.z * M * N : out;

    f32x4 acc[FM][FN] = {};

    auto stage = [&](int buf, int k0) {
#pragma unroll
        for (int i = 0; i < ACH; i++) {
            int chunk = i * THREADS + tid;
            int row = chunk / SLOTS, s = chunk % SLOTS, sg = s ^ (row & 7);
            gl_lds16(A + (size_t)(m0 + row) * K + kbase + k0 + sg * 8, &As[buf][chunk * 8]);
        }
#pragma unroll
        for (int i = 0; i < BCH; i++) {
            int chunk = i * THREADS + tid;
            int row = chunk / SLOTS, s = chunk % SLOTS, sg = s ^ (row & 7);
            gl_lds16(Bt + (size_t)(n0 + row) * K + kbase + k0 + sg * 8, &Bs[buf][chunk * 8]);
        }
    };

    int NT = Kc / BK;
    stage(0, 0);
    int cur = 0;
    for (int t = 0; t < NT; t++) {
        if (t + 1 < NT) { stage(cur ^ 1, (t + 1) * BK); s_vmcnt<LPS>(); }
        else            { s_vmcnt<0>(); }
        bar();      // tile t staged by all waves
        sfence();

        const u16* Ab = &As[cur][0];
        const u16* Bb = &Bs[cur][0];
        f16x8 af[FM][NKF], bfrag[FN][NKF];
#pragma unroll
        for (int m = 0; m < FM; m++)
#pragma unroll
            for (int kf = 0; kf < NKF; kf++) {
                int row = wm * WM + m * 16 + lr;
                af[m][kf] = *(const f16x8*)(Ab + row * BK + (((kf * 4 + g) ^ (row & 7)) * 8));
            }
#pragma unroll
        for (int n = 0; n < FN; n++)
#pragma unroll
            for (int kf = 0; kf < NKF; kf++) {
                int row = wn * WN + n * 16 + lr;
                bfrag[n][kf] = *(const f16x8*)(Bb + row * BK + (((kf * 4 + g) ^ (row & 7)) * 8));
            }
#pragma unroll
        for (int kf = 0; kf < NKF; kf++)
#pragma unroll
            for (int m = 0; m < FM; m++)
#pragma unroll
                for (int n = 0; n < FN; n++)
                    acc[m][n] = __builtin_amdgcn_mfma_f32_16x16x32_f16(
                        af[m][kf], bfrag[n][kf], acc[m][n], 0, 0, 0);

        sfence();
        bar();      // all waves done reading buf[cur] before re-stage
        cur ^= 1;
    }

#pragma unroll
    for (int m = 0; m < FM; m++) {
#pragma unroll
        for (int n = 0; n < FN; n++) {
            int col = n0 + wn * WN + n * 16 + lr;
            int row0 = m0 + wm * WM + m * 16 + 4 * g;
            float bv = (SPLITK > 1 && blockIdx.z != 0) ? 0.f : bias[col];
            u16 hv[4];
#pragma unroll
            for (int r = 0; r < 4; r++) {
                float v = acc[m][n][r] + bv;
                if (ACT) v = gelu_f(v);
                stv(&outz[(size_t)(row0 + r) * N + col], v);
                if (WVT) hv[r] = f2h(v);
            }
            if (WVT && col >= 2048) {
                ushort4 pv; pv.x = hv[0]; pv.y = hv[1]; pv.z = hv[2]; pv.w = hv[3];
                *(ushort4*)(vTout + (size_t)(col - 2048) * 1024 + row0) = pv;
            }
        }
    }
}

// ---------------- flash MFMA attention, KVBLK=128, 2-phase pipelined ----------------
__global__ __launch_bounds__(256) void attn_mfma(
    const u16* __restrict__ qkv, const u16* __restrict__ vT,
    const float* __restrict__ mask, u16* __restrict__ y) {
    int h = blockIdx.y;
    int q0 = blockIdx.x * 64;
    int tid = threadIdx.x;
    int w = tid >> 6, l = tid & 63;
    int lr = l & 15, g = l >> 4;

    __shared__ u16 Ks[2][128 * 64];   // [key][d], 8 slots/row
    __shared__ u16 Vs[2][64 * 128];   // [d][key], 16 slots/row
    __shared__ u16 Ps[4 * 16 * 128];  // per-wave P: [q][key], 16 slots/row
    __shared__ float maskb[1024];

    for (int i = tid; i < 1024; i += 256) maskb[i] = -1e9f * (1.f - mask[i]);
    s_lgkm0();

    f16x8 qf[2];
#pragma unroll
    for (int kf = 0; kf < 2; kf++)
        qf[kf] = *(const f16x8*)(qkv + (size_t)(q0 + w * 16 + lr) * 3072 + h * 64 + kf * 32 + g * 8);

    f32x4 o[4] = {};
    float mrow[4], lrow[4];
#pragma unroll
    for (int r = 0; r < 4; r++) { mrow[r] = -1e30f; lrow[r] = 0.f; }

    u16* Psw = Ps + w * 2048;

    auto stage = [&](int buf, int kc) {
#pragma unroll
        for (int i = 0; i < 4; i++) {
            int chunk = i * 256 + tid;
            int krow = chunk >> 3, ks = chunk & 7, ksg = ks ^ (krow & 7);
            gl_lds16(qkv + (size_t)(kc * 128 + krow) * 3072 + 1024 + h * 64 + ksg * 8,
                     &Ks[buf][chunk * 8]);
            int vrow = chunk >> 4, vs = chunk & 15, vsg = vs ^ (vrow & 7);
            gl_lds16(vT + (size_t)(h * 64 + vrow) * 1024 + kc * 128 + vsg * 8,
                     &Vs[buf][chunk * 8]);
        }
    };

    stage(0, 0);
    int cur = 0;
    for (int kc = 0; kc < 8; kc++) {
        if (kc + 1 < 8) { stage(cur ^ 1, kc + 1); s_vmcnt<8>(); }
        else            { s_vmcnt<0>(); }
        bar();
        sfence();
        const u16* Kb = &Ks[cur][0];
        const u16* Vb = &Vs[cur][0];

        f32x4 s[8] = {};
        __builtin_amdgcn_s_setprio(1);
#pragma unroll
        for (int n = 0; n < 8; n++)
#pragma unroll
            for (int kf = 0; kf < 2; kf++) {
                int row = n * 16 + lr;
                f16x8 kfrag = *(const f16x8*)(Kb + row * 64 + (((kf * 4 + g) ^ (row & 7)) * 8));
                s[n] = __builtin_amdgcn_mfma_f32_16x16x32_f16(qf[kf], kfrag, s[n], 0, 0, 0);
            }
        __builtin_amdgcn_s_setprio(0);

        float mcol[8];
#pragma unroll
        for (int n = 0; n < 8; n++) mcol[n] = maskb[kc * 128 + n * 16 + lr];

        float scl[4], mnew[4], psum[4];
#pragma unroll
        for (int r = 0; r < 4; r++) {
            float mx = -1e30f;
#pragma unroll
            for (int n = 0; n < 8; n++) {
                float sv = s[n][r] * 0.125f + mcol[n];
                s[n][r] = sv;
                mx = fmaxf(mx, sv);
            }
            mx = fmaxf(mx, __shfl_xor(mx, 1));
            mx = fmaxf(mx, __shfl_xor(mx, 2));
            mx = fmaxf(mx, __shfl_xor(mx, 4));
            mx = fmaxf(mx, __shfl_xor(mx, 8));
            mnew[r] = fmaxf(mrow[r], mx);
            scl[r] = __expf(mrow[r] - mnew[r]);
            mrow[r] = mnew[r];
            psum[r] = 0.f;
        }
#pragma unroll
        for (int n = 0; n < 8; n++) {
            float p0 = __expf(s[n][0] - mnew[0]);
            float p1 = __expf(s[n][1] - mnew[1]);
            float p2 = __expf(s[n][2] - mnew[2]);
            float p3 = __expf(s[n][3] - mnew[3]);
            psum[0] += p0; psum[1] += p1; psum[2] += p2; psum[3] += p3;
            int col = n * 16 + lr, cs = col >> 3, cl = col & 7;
            int r0 = 4 * g;
            Psw[(r0 + 0) * 128 + ((cs ^ ((r0 + 0) & 7)) * 8) + cl] = f2h(p0);
            Psw[(r0 + 1) * 128 + ((cs ^ ((r0 + 1) & 7)) * 8) + cl] = f2h(p1);
            Psw[(r0 + 2) * 128 + ((cs ^ ((r0 + 2) & 7)) * 8) + cl] = f2h(p2);
            Psw[(r0 + 3) * 128 + ((cs ^ ((r0 + 3) & 7)) * 8) + cl] = f2h(p3);
        }
#pragma unroll
        for (int r = 0; r < 4; r++) {
            float ps_ = psum[r];
            ps_ += __shfl_xor(ps_, 1);
            ps_ += __shfl_xor(ps_, 2);
            ps_ += __shfl_xor(ps_, 4);
            ps_ += __shfl_xor(ps_, 8);
            lrow[r] = lrow[r] * scl[r] + ps_;
#pragma unroll
            for (int dn = 0; dn < 4; dn++) o[dn][r] *= scl[r];
        }

        f16x8 pa[4];
#pragma unroll
        for (int kf = 0; kf < 4; kf++)
            pa[kf] = *(const f16x8*)(Psw + lr * 128 + (((kf * 4 + g) ^ (lr & 7)) * 8));
        __builtin_amdgcn_s_setprio(1);
#pragma unroll
        for (int dn = 0; dn < 4; dn++) {
#pragma unroll
            for (int kf = 0; kf < 4; kf++) {
                int row = dn * 16 + lr;
                f16x8 vb = *(const f16x8*)(Vb + row * 128 + (((kf * 4 + g) ^ (row & 7)) * 8));
                o[dn] = __builtin_amdgcn_mfma_f32_16x16x32_f16(pa[kf], vb, o[dn], 0, 0, 0);
            }
        }
        __builtin_amdgcn_s_setprio(0);

        sfence();
        bar();
        cur ^= 1;
    }

    float inv[4];
#pragma unroll
    for (int r = 0; r < 4; r++) inv[r] = 1.f / lrow[r];
#pragma unroll
    for (int dn = 0; dn < 4; dn++)
#pragma unroll
        for (int r = 0; r < 4; r++) {
            int row = q0 + w * 16 + 4 * g + r;
            int col = h * 64 + dn * 16 + lr;
            y[(size_t)row * 1024 + col] = f2h(o[dn][r] * inv[r]);
        }
}

// ---------------- launch ----------------
extern "C" void kernel_launch(void* const* d_in, const int* in_sizes, int n_in,
                              void* d_out, int out_size, void* d_ws, size_t ws_size,
                              hipStream_t stream) {
    const float* inputs_embeds = (const float*)d_in[0];
    const float* attn_mask     = (const float*)d_in[1];
    const float* ln1_g = (const float*)d_in[2];
    const float* ln1_b = (const float*)d_in[3];
    const float* Wqkv  = (const float*)d_in[4];
    const float* bqkv  = (const float*)d_in[5];
    const float* Wo    = (const float*)d_in[6];
    const float* bo    = (const float*)d_in[7];
    const float* ln2_g = (const float*)d_in[8];
    const float* ln2_b = (const float*)d_in[9];
    const float* Wfc   = (const float*)d_in[10];
    const float* bfc   = (const float*)d_in[11];
    const float* Wmp   = (const float*)d_in[12];
    const float* bmp   = (const float*)d_in[13];
    const float* lnf_g = (const float*)d_in[14];
    const float* lnf_b = (const float*)d_in[15];
    float* out = (float*)d_out;

    char* ws = (char*)d_ws;
    float* x   = (float*)ws;                              // 4 MB fp32 residual
    u16* hbuf  = (u16*)(ws + (4u << 20));                 // 2 MB fp16 (ln out / attn y)
    u16* qkvb  = (u16*)(ws + (6u << 20));                 // 8 MB (qkv 6MB | fc 8MB)
    u16* fcb   = qkvb;
    u16* ybuf  = hbuf;
    u16* vTb   = (u16*)(ws + (14u << 20));                // 2 MB [1024 d][1024 key]
    u16* wbuf0 = (u16*)(ws + (16u << 20));                // 24 MB weights (even layers)
    u16* wbuf1 = (u16*)(ws + (40u << 20));                // 24 MB weights (odd layers)
    float* pP  = (float*)(ws + (64u << 20));              // 8 MB proj partials (2x 4MB)
    float* pM  = (float*)(ws + (72u << 20));              // 8 MB MP partials   (2x 4MB)

    hipMemcpyAsync(x, inputs_embeds, (size_t)(1 << 20) * sizeof(float),
                   hipMemcpyDeviceToDevice, stream);

    // prologue: layer 0 weights -> wbuf0
    tr_cvt_all<<<3072, 256, 0, stream>>>(Wqkv, Wo, Wfc, Wmp, wbuf0);

    for (int l = 0; l < 12; l++) {
        u16* wb = (l & 1) ? wbuf1 : wbuf0;
        u16* wq = wb, *wo_ = wb + 3145728, *wf = wb + 4194304, *wm = wb + 8388608;

        bool cv = (l + 1 < 12);
        u16* nb = ((l + 1) & 1) ? wbuf1 : wbuf0;
        const float* nWq = cv ? Wqkv + (size_t)(l + 1) * 3145728 : nullptr;
        const float* nWo = cv ? Wo   + (size_t)(l + 1) * 1048576 : nullptr;
        const float* nWf = cv ? Wfc  + (size_t)(l + 1) * 4194304 : nullptr;
        const float* nWm = cv ? Wmp  + (size_t)(l + 1) * 4194304 : nullptr;
        int grid_ln = cv ? 256 + 1536 : 256;

        // ln1 (+ convert tiles 0..1535 of layer l+1); l>0 also reduces MP partials
        if (l == 0)
            ln_cvt<0, u16><<<grid_ln, 256, 0, stream>>>(
                x, nullptr, nullptr, ln1_g + l * 1024, ln1_b + l * 1024, hbuf,
                nWq, nWo, nWf, nWm, nb, 0);
        else
            ln_cvt<1, u16><<<grid_ln, 256, 0, stream>>>(
                x, pM, pM + (1 << 20), ln1_g + l * 1024, ln1_b + l * 1024, hbuf,
                nWq, nWo, nWf, nWm, nb, 0);

        // QKV: 1024x3072, 64x128 tiles, 8 waves (2x4) -> 384 blocks x 512 thr; fused vT
        gemm_f16<64, 128, 64, 2, 4, 0, 1, 1, u16><<<dim3(24, 16), 512, 0, stream>>>(
            hbuf, wq, bqkv + (size_t)l * 3072, qkvb, vTb, 1024, 3072, 1024);
        attn_mfma<<<dim3(16, 16), 256, 0, stream>>>(qkvb, vTb, attn_mask, ybuf);
        // proj: 1024x1024, 64x64 tiles, BK=128, splitK=2 -> 512 blocks, fp32 partials
        gemm_f16<64, 64, 128, 2, 2, 0, 0, 2, float><<<dim3(16, 16, 2), 256, 0, stream>>>(
            ybuf, wo_, bo + (size_t)l * 1024, pP, nullptr, 1024, 1024, 1024);
        // ln2 (+ convert tiles 1536..3071 of layer l+1); reduces proj partials
        ln_cvt<1, u16><<<grid_ln, 256, 0, stream>>>(
            x, pP, pP + (1 << 20), ln2_g + l * 1024, ln2_b + l * 1024, hbuf,
            nWq, nWo, nWf, nWm, nb, 1536);
        // FC: 1024x4096, 128x128 tiles, 8 waves (2x4) -> 256 blocks x 512 thr
        gemm_f16<128, 128, 64, 2, 4, 1, 0, 1, u16><<<dim3(32, 8), 512, 0, stream>>>(
            hbuf, wf, bfc + (size_t)l * 4096, fcb, nullptr, 1024, 4096, 1024);
        // MP: 1024x1024 (K=4096), 64x64 tiles, BK=128, splitK=2 -> 512 blocks
        gemm_f16<64, 64, 128, 2, 2, 0, 0, 2, float><<<dim3(16, 16, 2), 256, 0, stream>>>(
            fcb, wm, bmp + (size_t)l * 1024, pM, nullptr, 1024, 1024, 4096);
    }
    // final LN reduces layer-11 MP partials (no convert blocks)
    ln_cvt<1, float><<<256, 256, 0, stream>>>(
        x, pM, pM + (1 << 20), lnf_g, lnf_b, out,
        nullptr, nullptr, nullptr, nullptr, nullptr, 0);
}